// Round 1
// baseline (8856.024 us; speedup 1.0000x reference)
//
#include <hip/hip_runtime.h>
#include <hip/hip_bf16.h>
#include <math.h>

#define Cdim 512
#define Hn   8
#define HDim 64
#define Ld   4
#define Tn   1024
#define Bn   2
#define NTOK 2048   // B*T
#define FF   2048   // 4*C
#define Vn   32000

// ---------------- embedding: out[b,t,:] = tok[inp[b,t],:] + pos[t,:] ----------------
__global__ __launch_bounds__(256) void embed_k(const int* __restrict__ inp,
    const float* __restrict__ tok, const float* __restrict__ pos,
    float* __restrict__ out)
{
    int idx = blockIdx.x * 256 + threadIdx.x;   // over B*T*C
    int c  = idx & (Cdim - 1);
    int bt = idx >> 9;
    int t  = bt & (Tn - 1);
    out[idx] = tok[(long)inp[bt] * Cdim + c] + pos[t * Cdim + c];
}

// ---------------- layernorm over last dim (C=512), one block per row ----------------
__global__ __launch_bounds__(256) void ln_k(const float* __restrict__ x,
    const float* __restrict__ g, const float* __restrict__ bb,
    float* __restrict__ y)
{
    __shared__ float red[4];
    int row = blockIdx.x, tid = threadIdx.x;
    const float* xr = x + (long)row * Cdim;
    float v0 = xr[tid], v1 = xr[tid + 256];
    float s = v0 + v1;
    #pragma unroll
    for (int o = 32; o > 0; o >>= 1) s += __shfl_down(s, o, 64);
    int wid = tid >> 6, lane = tid & 63;
    if (lane == 0) red[wid] = s;
    __syncthreads();
    float mean = (red[0] + red[1] + red[2] + red[3]) * (1.f / Cdim);
    __syncthreads();
    float d0 = v0 - mean, d1 = v1 - mean;
    float qv = d0 * d0 + d1 * d1;
    #pragma unroll
    for (int o = 32; o > 0; o >>= 1) qv += __shfl_down(qv, o, 64);
    if (lane == 0) red[wid] = qv;
    __syncthreads();
    float var = (red[0] + red[1] + red[2] + red[3]) * (1.f / Cdim);
    float inv = rsqrtf(var + 1e-5f);
    y[(long)row * Cdim + tid]       = d0 * inv * g[tid]       + bb[tid];
    y[(long)row * Cdim + tid + 256] = d1 * inv * g[tid + 256] + bb[tid + 256];
}

// ------------- transpose [H,C,HD] -> [C, H*HD] so projections are one GEMM -------------
__global__ __launch_bounds__(256) void transw_k(const float* __restrict__ w,
    float* __restrict__ wt)
{
    int idx = blockIdx.x * 256 + threadIdx.x;   // over C*C = 262144
    int c = idx >> 9;
    int n = idx & 511;
    int hh = n >> 6, dd = n & 63;
    wt[idx] = w[((long)hh * Cdim + c) * HDim + dd];
}

// ---------------- tiled f32 GEMM: C = op(A @ B) [+bias][relu][+res] -----------------
// 64x64 tile, BK=16, 256 threads, 4x4 per thread. Strided-batched via blockIdx.z:
// z -> (zb, zh) with per-dim offsets; pass HB=1 / offs=0 for plain GEMM.
template<bool TRANSB, bool HAS_BIAS, bool RELU, bool HAS_RES>
__global__ __launch_bounds__(256) void gemm_k(
    const float* __restrict__ A, const float* __restrict__ B,
    const float* __restrict__ bias, const float* __restrict__ res,
    float* __restrict__ C_,
    int M, int N, int K, int lda, int ldb, int ldc,
    long aOffB, long aOffH, long bOffB, long bOffH, long cOffB, long cOffH, int HB)
{
    int bz = blockIdx.z;
    int zb = bz / HB, zh = bz % HB;
    A  += zb * aOffB + zh * aOffH;
    B  += zb * bOffB + zh * bOffH;
    C_ += zb * cOffB + zh * cOffH;
    const float* resp = res;
    if (HAS_RES) resp += zb * cOffB + zh * cOffH;

    __shared__ float As[16][65];   // +1 pad: avoids 16-way bank conflict on strided store
    __shared__ float Bs[16][65];

    int bm = blockIdx.y * 64, bn = blockIdx.x * 64;
    int tid = threadIdx.x;
    int tx = tid & 15, ty = tid >> 4;
    float acc[4][4] = {};

    for (int k0 = 0; k0 < K; k0 += 16) {
        #pragma unroll
        for (int i = 0; i < 4; i++) {
            int e = tid + i * 256;
            int r = e >> 4, c = e & 15;
            As[c][r] = A[(long)(bm + r) * lda + (k0 + c)];
        }
        #pragma unroll
        for (int i = 0; i < 4; i++) {
            int e = tid + i * 256;
            if (!TRANSB) {
                int r = e >> 6, c = e & 63;
                Bs[r][c] = B[(long)(k0 + r) * ldb + (bn + c)];
            } else {
                int c = e >> 4, r = e & 15;
                Bs[r][c] = B[(long)(bn + c) * ldb + (k0 + r)];
            }
        }
        __syncthreads();
        #pragma unroll
        for (int kk = 0; kk < 16; kk++) {
            float a_[4], b_[4];
            #pragma unroll
            for (int i = 0; i < 4; i++) a_[i] = As[kk][ty * 4 + i];
            #pragma unroll
            for (int j = 0; j < 4; j++) b_[j] = Bs[kk][tx * 4 + j];
            #pragma unroll
            for (int i = 0; i < 4; i++)
                #pragma unroll
                for (int j = 0; j < 4; j++)
                    acc[i][j] = fmaf(a_[i], b_[j], acc[i][j]);
        }
        __syncthreads();
    }

    #pragma unroll
    for (int i = 0; i < 4; i++) {
        int r = bm + ty * 4 + i;
        long rowoff = (long)r * ldc;
        #pragma unroll
        for (int j = 0; j < 4; j++) {
            int cc = bn + tx * 4 + j;
            float vv = acc[i][j];
            if (HAS_BIAS) vv += bias[cc];
            if (RELU)     vv = fmaxf(vv, 0.f);
            if (HAS_RES)  vv += resp[rowoff + cc];
            C_[rowoff + cc] = vv;
        }
    }
}

// --------- softmax over rows of scores [B,H,T,S=1024], scale + causal/enc-mask ---------
template<bool CAUSAL, bool HAS_MASK>
__global__ __launch_bounds__(256) void softmax_k(float* __restrict__ s,
    const int* __restrict__ mask)
{
    __shared__ float red[4];
    int row = blockIdx.x;             // over B*H*T
    int t = row & (Tn - 1);
    int b = row >> 13;                // / (H*T)
    float* sr = s + (long)row * Tn;
    int tid = threadIdx.x;
    const float scale = 0.125f;       // HD^-0.5
    float vals[4];
    float mx = -INFINITY;
    #pragma unroll
    for (int i = 0; i < 4; i++) {
        int idx = tid + i * 256;
        float vv = sr[idx] * scale;
        bool ok = true;
        if (CAUSAL && idx > t) ok = false;
        if (HAS_MASK && mask[b * Tn + idx] == 0) ok = false;
        vv = ok ? vv : -INFINITY;
        vals[i] = vv;
        mx = fmaxf(mx, vv);
    }
    #pragma unroll
    for (int o = 32; o > 0; o >>= 1) mx = fmaxf(mx, __shfl_down(mx, o, 64));
    int wid = tid >> 6, lane = tid & 63;
    if (lane == 0) red[wid] = mx;
    __syncthreads();
    mx = fmaxf(fmaxf(red[0], red[1]), fmaxf(red[2], red[3]));
    __syncthreads();
    float sum = 0.f;
    #pragma unroll
    for (int i = 0; i < 4; i++) {
        float e = __expf(vals[i] - mx);
        e = (vals[i] == -INFINITY) ? 0.f : e;
        vals[i] = e;
        sum += e;
    }
    #pragma unroll
    for (int o = 32; o > 0; o >>= 1) sum += __shfl_down(sum, o, 64);
    if (lane == 0) red[wid] = sum;
    __syncthreads();
    sum = red[0] + red[1] + red[2] + red[3];
    float inv = 1.f / sum;
    #pragma unroll
    for (int i = 0; i < 4; i++) sr[tid + i * 256] = vals[i] * inv;
}

// ================================ host orchestration ================================
static void run_attention(hipStream_t stream,
    const float* hq_in, const float* hkv_in,
    const float* wqp, const float* wkp, const float* wvp,
    const float* wop, const float* bop,
    float* xres, const int* mask, bool causal,
    float* q, float* k, float* v, float* ao, float* sc,
    float* wqt, float* wkt, float* wvt)
{
    dim3 blk(256);
    transw_k<<<1024, blk, 0, stream>>>(wqp, wqt);
    transw_k<<<1024, blk, 0, stream>>>(wkp, wkt);
    transw_k<<<1024, blk, 0, stream>>>(wvp, wvt);
    // projections: [NTOK,C] @ [C,C] -> [B,T,H,HD] (flat [NTOK, C])
    gemm_k<false,false,false,false><<<dim3(Cdim/64, NTOK/64, 1), blk, 0, stream>>>(
        hq_in, wqt, nullptr, nullptr, q, NTOK, Cdim, Cdim, Cdim, Cdim, Cdim,
        0,0,0,0,0,0, 1);
    gemm_k<false,false,false,false><<<dim3(Cdim/64, NTOK/64, 1), blk, 0, stream>>>(
        hkv_in, wkt, nullptr, nullptr, k, NTOK, Cdim, Cdim, Cdim, Cdim, Cdim,
        0,0,0,0,0,0, 1);
    gemm_k<false,false,false,false><<<dim3(Cdim/64, NTOK/64, 1), blk, 0, stream>>>(
        hkv_in, wvt, nullptr, nullptr, v, NTOK, Cdim, Cdim, Cdim, Cdim, Cdim,
        0,0,0,0,0,0, 1);
    // scores[b,h,t,s] = q . k  (batched over b,h; B-operand transposed)
    gemm_k<true,false,false,false><<<dim3(Tn/64, Tn/64, Bn*Hn), blk, 0, stream>>>(
        q, k, nullptr, nullptr, sc, Tn, Tn, HDim, Cdim, Cdim, Tn,
        (long)Tn*Cdim, HDim, (long)Tn*Cdim, HDim, (long)Hn*Tn*Tn, (long)Tn*Tn, Hn);
    if (causal)
        softmax_k<true,false><<<Bn*Hn*Tn, blk, 0, stream>>>(sc, nullptr);
    else
        softmax_k<false,true><<<Bn*Hn*Tn, blk, 0, stream>>>(sc, mask);
    // o[b,t,h,d] = P @ V  (batched)
    gemm_k<false,false,false,false><<<dim3(HDim/64, Tn/64, Bn*Hn), blk, 0, stream>>>(
        sc, v, nullptr, nullptr, ao, Tn, HDim, Tn, Tn, Cdim, Cdim,
        (long)Hn*Tn*Tn, (long)Tn*Tn, (long)Tn*Cdim, HDim, (long)Tn*Cdim, HDim, Hn);
    // out projection + bias + residual (in place on xres)
    gemm_k<false,true,false,true><<<dim3(Cdim/64, NTOK/64, 1), blk, 0, stream>>>(
        ao, wop, bop, xres, xres, NTOK, Cdim, Cdim, Cdim, Cdim, Cdim,
        0,0,0,0,0,0, 1);
}

extern "C" void kernel_launch(void* const* d_in, const int* in_sizes, int n_in,
                              void* d_out, int out_size, void* d_ws, size_t ws_size,
                              hipStream_t stream)
{
    (void)in_sizes; (void)n_in; (void)out_size; (void)ws_size;
    const int*   enc_inp  = (const int*)d_in[0];
    const int*   dec_inp  = (const int*)d_in[1];
    const int*   enc_mask = (const int*)d_in[2];
    const float* tok_emb  = (const float*)d_in[3];
    const float* pos_emb  = (const float*)d_in[4];
    const float* e_wq  = (const float*)d_in[5];
    const float* e_wk  = (const float*)d_in[6];
    const float* e_wv  = (const float*)d_in[7];
    const float* e_wo  = (const float*)d_in[8];
    const float* e_bo  = (const float*)d_in[9];
    const float* dsa_wq = (const float*)d_in[10];
    const float* dsa_wk = (const float*)d_in[11];
    const float* dsa_wv = (const float*)d_in[12];
    const float* dsa_wo = (const float*)d_in[13];
    const float* dsa_bo = (const float*)d_in[14];
    const float* dca_wq = (const float*)d_in[15];
    const float* dca_wk = (const float*)d_in[16];
    const float* dca_wv = (const float*)d_in[17];
    const float* dca_wo = (const float*)d_in[18];
    const float* dca_bo = (const float*)d_in[19];
    const float* e_ln1_g = (const float*)d_in[20];
    const float* e_ln1_b = (const float*)d_in[21];
    const float* e_ln2_g = (const float*)d_in[22];
    const float* e_ln2_b = (const float*)d_in[23];
    const float* d_ln1_g = (const float*)d_in[24];
    const float* d_ln1_b = (const float*)d_in[25];
    const float* d_ln2_g = (const float*)d_in[26];
    const float* d_ln2_b = (const float*)d_in[27];
    const float* d_ln3_g = (const float*)d_in[28];
    const float* d_ln3_b = (const float*)d_in[29];
    const float* e_w1 = (const float*)d_in[30];
    const float* e_b1 = (const float*)d_in[31];
    const float* e_w2 = (const float*)d_in[32];
    const float* e_b2 = (const float*)d_in[33];
    const float* d_w1 = (const float*)d_in[34];
    const float* d_b1 = (const float*)d_in[35];
    const float* d_w2 = (const float*)d_in[36];
    const float* d_b2 = (const float*)d_in[37];
    const float* out_w = (const float*)d_in[38];
    const float* out_b = (const float*)d_in[39];
    float* out = (float*)d_out;

    // -------- workspace carve (floats); total ~30.1M floats = ~115 MB --------
    float* ws    = (float*)d_ws;
    float* x_enc = ws;                       // 1048576  (becomes enc_out)
    float* x_dec = x_enc + 1048576;          // 1048576
    float* h     = x_dec + 1048576;          // 1048576
    float* hk    = h     + 1048576;          // 1048576
    float* q     = hk    + 1048576;          // 1048576
    float* k     = q     + 1048576;          // 1048576
    float* v     = k     + 1048576;          // 1048576
    float* ao    = v     + 1048576;          // 1048576
    float* mid   = ao    + 1048576;          // 4194304
    float* sc    = mid   + 4194304;          // 16777216
    float* wqt   = sc    + 16777216;         // 262144
    float* wkt   = wqt   + 262144;           // 262144
    float* wvt   = wkt   + 262144;           // 262144

    dim3 blk(256);
    const long WQKV = (long)Hn * Cdim * HDim;   // 262144 per layer
    const long WO   = (long)Cdim * Cdim;        // 262144
    const long W1   = (long)Cdim * FF;          // 1048576
    const long W2   = (long)FF * Cdim;          // 1048576

    // ================= encoder =================
    embed_k<<<NTOK * Cdim / 256, blk, 0, stream>>>(enc_inp, tok_emb, pos_emb, x_enc);
    for (int l = 0; l < Ld; l++) {
        ln_k<<<NTOK, blk, 0, stream>>>(x_enc, e_ln1_g + l * Cdim, e_ln1_b + l * Cdim, h);
        run_attention(stream, h, h,
                      e_wq + l * WQKV, e_wk + l * WQKV, e_wv + l * WQKV,
                      e_wo + l * WO, e_bo + l * Cdim,
                      x_enc, enc_mask, /*causal=*/false,
                      q, k, v, ao, sc, wqt, wkt, wvt);
        ln_k<<<NTOK, blk, 0, stream>>>(x_enc, e_ln2_g + l * Cdim, e_ln2_b + l * Cdim, h);
        gemm_k<false,true,true,false><<<dim3(FF/64, NTOK/64, 1), blk, 0, stream>>>(
            h, e_w1 + l * W1, e_b1 + l * FF, nullptr, mid,
            NTOK, FF, Cdim, Cdim, FF, FF, 0,0,0,0,0,0, 1);
        gemm_k<false,true,false,true><<<dim3(Cdim/64, NTOK/64, 1), blk, 0, stream>>>(
            mid, e_w2 + l * W2, e_b2 + l * Cdim, x_enc, x_enc,
            NTOK, Cdim, FF, FF, Cdim, Cdim, 0,0,0,0,0,0, 1);
    }
    // x_enc now holds enc_out (decoder only reads it)

    // ================= decoder =================
    embed_k<<<NTOK * Cdim / 256, blk, 0, stream>>>(dec_inp, tok_emb, pos_emb, x_dec);
    for (int l = 0; l < Ld; l++) {
        // causal self-attention
        ln_k<<<NTOK, blk, 0, stream>>>(x_dec, d_ln1_g + l * Cdim, d_ln1_b + l * Cdim, h);
        run_attention(stream, h, h,
                      dsa_wq + l * WQKV, dsa_wk + l * WQKV, dsa_wv + l * WQKV,
                      dsa_wo + l * WO, dsa_bo + l * Cdim,
                      x_dec, nullptr, /*causal=*/true,
                      q, k, v, ao, sc, wqt, wkt, wvt);
        // cross-attention (same LN applied to x and enc_out)
        ln_k<<<NTOK, blk, 0, stream>>>(x_dec, d_ln2_g + l * Cdim, d_ln2_b + l * Cdim, h);
        ln_k<<<NTOK, blk, 0, stream>>>(x_enc, d_ln2_g + l * Cdim, d_ln2_b + l * Cdim, hk);
        run_attention(stream, h, hk,
                      dca_wq + l * WQKV, dca_wk + l * WQKV, dca_wv + l * WQKV,
                      dca_wo + l * WO, dca_bo + l * Cdim,
                      x_dec, enc_mask, /*causal=*/false,
                      q, k, v, ao, sc, wqt, wkt, wvt);
        // FFN
        ln_k<<<NTOK, blk, 0, stream>>>(x_dec, d_ln3_g + l * Cdim, d_ln3_b + l * Cdim, h);
        gemm_k<false,true,true,false><<<dim3(FF/64, NTOK/64, 1), blk, 0, stream>>>(
            h, d_w1 + l * W1, d_b1 + l * FF, nullptr, mid,
            NTOK, FF, Cdim, Cdim, FF, FF, 0,0,0,0,0,0, 1);
        gemm_k<false,true,false,true><<<dim3(Cdim/64, NTOK/64, 1), blk, 0, stream>>>(
            mid, d_w2 + l * W2, d_b2 + l * Cdim, x_dec, x_dec,
            NTOK, Cdim, FF, FF, Cdim, Cdim, 0,0,0,0,0,0, 1);
    }

    // ================= final logits =================
    gemm_k<false,true,false,false><<<dim3(Vn/64, NTOK/64, 1), blk, 0, stream>>>(
        x_dec, out_w, out_b, nullptr, out,
        NTOK, Vn, Cdim, Cdim, Vn, Vn, 0,0,0,0,0,0, 1);
}

// Round 2
// 2015.921 us; speedup vs baseline: 4.3930x; 4.3930x over previous
//
#include <hip/hip_runtime.h>
#include <hip/hip_bf16.h>
#include <math.h>

#define Cdim 512
#define Hn   8
#define HDim 64
#define Ld   4
#define Tn   1024
#define Bn   2
#define NTOK 2048   // B*T
#define FF   2048   // 4*C
#define Vn   32000

typedef __bf16 bf16_t;
typedef __bf16 bf16x8 __attribute__((ext_vector_type(8)));
typedef __bf16 bf16x4 __attribute__((ext_vector_type(4)));
typedef float  f32x4  __attribute__((ext_vector_type(4)));

// ---------------- embedding: out[b,t,:] = tok[inp[b,t],:] + pos[t,:] (f32) ----------------
__global__ __launch_bounds__(256) void embed_k(const int* __restrict__ inp,
    const float* __restrict__ tok, const float* __restrict__ pos,
    float* __restrict__ out)
{
    int idx = blockIdx.x * 256 + threadIdx.x;   // over B*T*C
    int c  = idx & (Cdim - 1);
    int bt = idx >> 9;
    int t  = bt & (Tn - 1);
    out[idx] = tok[(long)inp[bt] * Cdim + c] + pos[t * Cdim + c];
}

// ---------------- layernorm (C=512): f32 in, bf16 out. one block per row ----------------
__global__ __launch_bounds__(256) void ln_k(const float* __restrict__ x,
    const float* __restrict__ g, const float* __restrict__ bb,
    bf16_t* __restrict__ y)
{
    __shared__ float red[4];
    int row = blockIdx.x, tid = threadIdx.x;
    const float* xr = x + (long)row * Cdim;
    float v0 = xr[tid], v1 = xr[tid + 256];
    float s = v0 + v1;
    #pragma unroll
    for (int o = 32; o > 0; o >>= 1) s += __shfl_down(s, o, 64);
    int wid = tid >> 6, lane = tid & 63;
    if (lane == 0) red[wid] = s;
    __syncthreads();
    float mean = (red[0] + red[1] + red[2] + red[3]) * (1.f / Cdim);
    __syncthreads();
    float d0 = v0 - mean, d1 = v1 - mean;
    float qv = d0 * d0 + d1 * d1;
    #pragma unroll
    for (int o = 32; o > 0; o >>= 1) qv += __shfl_down(qv, o, 64);
    if (lane == 0) red[wid] = qv;
    __syncthreads();
    float var = (red[0] + red[1] + red[2] + red[3]) * (1.f / Cdim);
    float inv = rsqrtf(var + 1e-5f);
    y[(long)row * Cdim + tid]       = (bf16_t)(d0 * inv * g[tid]       + bb[tid]);
    y[(long)row * Cdim + tid + 256] = (bf16_t)(d1 * inv * g[tid + 256] + bb[tid + 256]);
}

// ---------------- f32 -> bf16 elementwise convert ----------------
__global__ __launch_bounds__(256) void cvt_k(const float* __restrict__ x, bf16_t* __restrict__ y)
{
    int i = blockIdx.x * 256 + threadIdx.x;
    y[i] = (bf16_t)x[i];
}

// ------- tiled transpose+convert: f32 [R,Cc] -> bf16 [Cc,R]; two-level batch (zb,zh) -------
__global__ __launch_bounds__(256) void tcvt_k(const float* __restrict__ in,
    bf16_t* __restrict__ outp, int R, int Cc,
    long inOffB, long inOffH, long outOffB, long outOffH, int HB)
{
    int bz = blockIdx.z; int zb = bz / HB, zh = bz - zb * HB;
    in   += zb * inOffB  + zh * inOffH;
    outp += zb * outOffB + zh * outOffH;
    __shared__ float t[64][65];
    int r0 = blockIdx.y * 64, c0 = blockIdx.x * 64;
    int tx = threadIdx.x & 63, ty = threadIdx.x >> 6;
    #pragma unroll
    for (int i = 0; i < 16; i++)
        t[ty + i * 4][tx] = in[(long)(r0 + ty + i * 4) * Cc + c0 + tx];
    __syncthreads();
    #pragma unroll
    for (int i = 0; i < 16; i++) {
        int cc = ty + i * 4;
        outp[(long)(c0 + cc) * R + r0 + tx] = (bf16_t)t[tx][cc];
    }
}

// ------- V transpose: qkv[b,s,1024+h*64+d] (bf16) -> vt[(b*8+h)*64 + d][s] (bf16) -------
__global__ __launch_bounds__(256) void vtrans_k(const bf16_t* __restrict__ qkv,
    bf16_t* __restrict__ vt)
{
    __shared__ bf16_t t[64][72];
    int bh = blockIdx.y;
    int b = bh >> 3, h = bh & 7;
    int s0 = blockIdx.x * 64;
    int tx = threadIdx.x & 63, ty = threadIdx.x >> 6;
    const bf16_t* src = qkv + (long)b * Tn * 1536 + 1024 + h * 64;
    #pragma unroll
    for (int i = 0; i < 16; i++)
        t[ty + i * 4][tx] = src[(long)(s0 + ty + i * 4) * 1536 + tx];
    __syncthreads();
    bf16_t* dst = vt + (long)bh * 64 * Tn;
    #pragma unroll
    for (int i = 0; i < 16; i++) {
        int d = ty + i * 4;
        dst[(long)d * Tn + s0 + tx] = t[tx][d];
    }
}

// ================= bf16 MFMA GEMM: C = op(A @ Bt^T) =================
// A [M,K] bf16 row-major (lda), Bt [N,K] bf16 row-major (ldb).
// BM x BN tile, BK=32, 256 threads = 4 waves (2x2), 16x16x32 MFMA.
// global_load_lds width-16 staging, linear LDS. Batched via blockIdx.z -> (zb,zh).
template<int BM, int BN, bool BIAS, bool RELU, bool RES, bool OBF>
__global__ __launch_bounds__(256) void mgemm_k(
    const bf16_t* __restrict__ A, const bf16_t* __restrict__ Bt,
    const float* __restrict__ bias, const float* __restrict__ res,
    void* __restrict__ Cout,
    int K, int lda, int ldb, int ldc,
    long aOffB, long aOffH, long bOffB, long bOffH, long cOffB, long cOffH, int HB)
{
    int bz = blockIdx.z;
    int zb = bz / HB, zh = bz - zb * HB;
    A  += zb * aOffB + zh * aOffH;
    Bt += zb * bOffB + zh * bOffH;
    long coff = zb * cOffB + zh * cOffH;

    constexpr int MR = BM / 32;     // 16x16 m-frags per wave
    constexpr int NR = BN / 32;
    __shared__ bf16_t As[BM * 32];
    __shared__ bf16_t Bs[BN * 32];

    int tid = threadIdx.x;
    int wv = tid >> 6, lane = tid & 63;
    int bm = blockIdx.y * BM, bn = blockIdx.x * BN;
    int wr = wv >> 1, wc = wv & 1;

    f32x4 acc[MR][NR];
    #pragma unroll
    for (int i = 0; i < MR; i++)
        #pragma unroll
        for (int j = 0; j < NR; j++)
            acc[i][j] = (f32x4){0.f, 0.f, 0.f, 0.f};

    const int srow  = lane >> 2;        // 0..15 within a 16-row staging slab
    const int scol8 = (lane & 3) * 8;   // bf16 element offset within row
    const int r16 = lane & 15, kg8 = (lane >> 4) * 8;

    for (int k0 = 0; k0 < K; k0 += 32) {
        // ---- stage A tile [BM][32] ----
        #pragma unroll
        for (int j = 0; j < BM / 64; j++) {
            int rbase = wv * (BM / 4) + j * 16;
            const bf16_t* g = A + (long)(bm + rbase + srow) * lda + (k0 + scol8);
            __builtin_amdgcn_global_load_lds(
                (const __attribute__((address_space(1))) void*)g,
                (__attribute__((address_space(3))) void*)&As[rbase * 32],
                16, 0, 0);
        }
        // ---- stage Bt tile [BN][32] ----
        #pragma unroll
        for (int j = 0; j < BN / 64; j++) {
            int rbase = wv * (BN / 4) + j * 16;
            const bf16_t* g = Bt + (long)(bn + rbase + srow) * ldb + (k0 + scol8);
            __builtin_amdgcn_global_load_lds(
                (const __attribute__((address_space(1))) void*)g,
                (__attribute__((address_space(3))) void*)&Bs[rbase * 32],
                16, 0, 0);
        }
        __syncthreads();   // compiler drains vmcnt before barrier

        bf16x8 af[MR], bfv[NR];
        #pragma unroll
        for (int i = 0; i < MR; i++)
            af[i] = *(const bf16x8*)&As[(wr * (BM / 2) + i * 16 + r16) * 32 + kg8];
        #pragma unroll
        for (int j = 0; j < NR; j++)
            bfv[j] = *(const bf16x8*)&Bs[(wc * (BN / 2) + j * 16 + r16) * 32 + kg8];
        #pragma unroll
        for (int i = 0; i < MR; i++)
            #pragma unroll
            for (int j = 0; j < NR; j++)
                acc[i][j] = __builtin_amdgcn_mfma_f32_16x16x32_bf16(af[i], bfv[j], acc[i][j], 0, 0, 0);
        __syncthreads();
    }

    // ---- epilogue: C/D layout col=lane&15, row=(lane>>4)*4+q ----
    int crow0 = (lane >> 4) * 4;
    int ccol  = lane & 15;
    #pragma unroll
    for (int i = 0; i < MR; i++) {
        #pragma unroll
        for (int j = 0; j < NR; j++) {
            int gr = bm + wr * (BM / 2) + i * 16 + crow0;
            int gc = bn + wc * (BN / 2) + j * 16 + ccol;
            float bv = BIAS ? bias[gc] : 0.f;
            #pragma unroll
            for (int q = 0; q < 4; q++) {
                float v = acc[i][j][q];
                if (BIAS) v += bv;
                if (RELU) v = fmaxf(v, 0.f);
                long oidx = coff + (long)(gr + q) * ldc + gc;
                if (RES)  v += res[oidx];
                if (OBF) ((bf16_t*)Cout)[oidx] = (bf16_t)v;
                else     ((float*) Cout)[oidx] = v;
            }
        }
    }
}

// --------- softmax over bf16 score rows [B,H,T,S=1024], in-place, scale+mask ---------
template<bool CAUSAL, bool HAS_MASK>
__global__ __launch_bounds__(256) void softmax_bk(bf16_t* __restrict__ s,
    const int* __restrict__ mask)
{
    __shared__ float red[4];
    int row = blockIdx.x;             // over B*H*T
    int t = row & (Tn - 1);
    int b = row >> 13;
    bf16_t* sr = s + (long)row * Tn;
    int tid = threadIdx.x;
    const float scale = 0.125f;       // HD^-0.5
    ushort4 raw = *(const ushort4*)&sr[tid * 4];
    unsigned us[4] = {raw.x, raw.y, raw.z, raw.w};
    float vals[4];
    float mx = -INFINITY;
    #pragma unroll
    for (int i = 0; i < 4; i++) {
        int idx = tid * 4 + i;
        float vv = __uint_as_float(us[i] << 16) * scale;
        bool ok = true;
        if (CAUSAL && idx > t) ok = false;
        if (HAS_MASK && mask[b * Tn + idx] == 0) ok = false;
        vv = ok ? vv : -INFINITY;
        vals[i] = vv;
        mx = fmaxf(mx, vv);
    }
    #pragma unroll
    for (int o = 32; o > 0; o >>= 1) mx = fmaxf(mx, __shfl_down(mx, o, 64));
    int wid = tid >> 6, lane = tid & 63;
    if (lane == 0) red[wid] = mx;
    __syncthreads();
    mx = fmaxf(fmaxf(red[0], red[1]), fmaxf(red[2], red[3]));
    __syncthreads();
    float sum = 0.f;
    #pragma unroll
    for (int i = 0; i < 4; i++) {
        float e = __expf(vals[i] - mx);
        e = (vals[i] == -INFINITY) ? 0.f : e;
        vals[i] = e;
        sum += e;
    }
    #pragma unroll
    for (int o = 32; o > 0; o >>= 1) sum += __shfl_down(sum, o, 64);
    if (lane == 0) red[wid] = sum;
    __syncthreads();
    sum = red[0] + red[1] + red[2] + red[3];
    float inv = 1.f / sum;
    *(bf16x4*)&sr[tid * 4] = (bf16x4){
        (bf16_t)(vals[0] * inv), (bf16_t)(vals[1] * inv),
        (bf16_t)(vals[2] * inv), (bf16_t)(vals[3] * inv)};
}

// ================================ host orchestration ================================
static void run_attn(hipStream_t stream, const bf16_t* hq, const bf16_t* hkv,
    const bf16_t* wqkv, const float* bo, const bf16_t* wo_t,
    float* xres, const int* mask, bool causal,
    bf16_t* qkv, bf16_t* vt, bf16_t* sc, bf16_t* ao)
{
    dim3 blk(256);
    // q projection: N=512
    mgemm_k<128,128,false,false,false,true><<<dim3(4, 16, 1), blk, 0, stream>>>(
        hq, wqkv, nullptr, nullptr, qkv,
        Cdim, Cdim, Cdim, 1536, 0,0,0,0,0,0, 1);
    // k,v projection: N=1024
    mgemm_k<128,128,false,false,false,true><<<dim3(8, 16, 1), blk, 0, stream>>>(
        hkv, wqkv + 512 * Cdim, nullptr, nullptr, qkv + 512,
        Cdim, Cdim, Cdim, 1536, 0,0,0,0,0,0, 1);
    vtrans_k<<<dim3(16, 16), blk, 0, stream>>>(qkv, vt);
    // scores = q @ k^T, batched over (b,h)
    mgemm_k<128,128,false,false,false,true><<<dim3(8, 8, 16), blk, 0, stream>>>(
        qkv, qkv + 512, nullptr, nullptr, sc,
        HDim, 1536, 1536, Tn,
        (long)Tn * 1536, 64, (long)Tn * 1536, 64, (long)Hn * Tn * Tn, (long)Tn * Tn, Hn);
    if (causal)
        softmax_bk<true,false><<<Bn * Hn * Tn, blk, 0, stream>>>(sc, nullptr);
    else
        softmax_bk<false,true><<<Bn * Hn * Tn, blk, 0, stream>>>(sc, mask);
    // out = P @ V  (Bt = vt [64, S]), batched
    mgemm_k<128,64,false,false,false,true><<<dim3(1, 8, 16), blk, 0, stream>>>(
        sc, vt, nullptr, nullptr, ao,
        Tn, Tn, Tn, Cdim,
        (long)Hn * Tn * Tn, (long)Tn * Tn, (long)Hn * 64 * Tn, (long)64 * Tn,
        (long)Tn * Cdim, 64, Hn);
    // out projection + bias + residual (f32, in place on xres)
    mgemm_k<128,128,true,false,true,false><<<dim3(4, 16, 1), blk, 0, stream>>>(
        ao, wo_t, bo, xres, xres,
        Cdim, Cdim, Cdim, Cdim, 0,0,0,0,0,0, 1);
}

extern "C" void kernel_launch(void* const* d_in, const int* in_sizes, int n_in,
                              void* d_out, int out_size, void* d_ws, size_t ws_size,
                              hipStream_t stream)
{
    (void)in_sizes; (void)n_in; (void)out_size; (void)ws_size;
    const int*   enc_inp  = (const int*)d_in[0];
    const int*   dec_inp  = (const int*)d_in[1];
    const int*   enc_mask = (const int*)d_in[2];
    const float* tok_emb  = (const float*)d_in[3];
    const float* pos_emb  = (const float*)d_in[4];
    const float* e_wq  = (const float*)d_in[5];
    const float* e_wk  = (const float*)d_in[6];
    const float* e_wv  = (const float*)d_in[7];
    const float* e_wo  = (const float*)d_in[8];
    const float* e_bo  = (const float*)d_in[9];
    const float* dsa_wq = (const float*)d_in[10];
    const float* dsa_wk = (const float*)d_in[11];
    const float* dsa_wv = (const float*)d_in[12];
    const float* dsa_wo = (const float*)d_in[13];
    const float* dsa_bo = (const float*)d_in[14];
    const float* dca_wq = (const float*)d_in[15];
    const float* dca_wk = (const float*)d_in[16];
    const float* dca_wv = (const float*)d_in[17];
    const float* dca_wo = (const float*)d_in[18];
    const float* dca_bo = (const float*)d_in[19];
    const float* e_ln1_g = (const float*)d_in[20];
    const float* e_ln1_b = (const float*)d_in[21];
    const float* e_ln2_g = (const float*)d_in[22];
    const float* e_ln2_b = (const float*)d_in[23];
    const float* d_ln1_g = (const float*)d_in[24];
    const float* d_ln1_b = (const float*)d_in[25];
    const float* d_ln2_g = (const float*)d_in[26];
    const float* d_ln2_b = (const float*)d_in[27];
    const float* d_ln3_g = (const float*)d_in[28];
    const float* d_ln3_b = (const float*)d_in[29];
    const float* e_w1 = (const float*)d_in[30];
    const float* e_b1 = (const float*)d_in[31];
    const float* e_w2 = (const float*)d_in[32];
    const float* e_b2 = (const float*)d_in[33];
    const float* d_w1 = (const float*)d_in[34];
    const float* d_b1 = (const float*)d_in[35];
    const float* d_w2 = (const float*)d_in[36];
    const float* d_b2 = (const float*)d_in[37];
    const float* out_w = (const float*)d_in[38];
    const float* out_b = (const float*)d_in[39];
    float* out = (float*)d_out;

    // -------- workspace carve (bytes) --------
    char* p = (char*)d_ws;
    auto takeB = [&](size_t bytes) { char* r = p; p += (bytes + 255) & ~(size_t)255; return r; };
    float*  x_enc = (float*)takeB(1048576ull * 4);
    float*  x_dec = (float*)takeB(1048576ull * 4);
    bf16_t* h     = (bf16_t*)takeB(1048576ull * 2);
    bf16_t* hk    = (bf16_t*)takeB(1048576ull * 2);
    bf16_t* qkv   = (bf16_t*)takeB(3145728ull * 2);
    bf16_t* vt    = (bf16_t*)takeB(1048576ull * 2);
    bf16_t* ao    = (bf16_t*)takeB(1048576ull * 2);
    bf16_t* xdb   = (bf16_t*)takeB(1048576ull * 2);
    bf16_t* mid   = (bf16_t*)takeB(4194304ull * 2);
    bf16_t* sc    = (bf16_t*)takeB(16777216ull * 2);
    bf16_t* wqkv_t = (bf16_t*)takeB(12ull * 786432 * 2);
    bf16_t* wo_t   = (bf16_t*)takeB(12ull * 262144 * 2);
    bf16_t* w1_t   = (bf16_t*)takeB(8ull * 1048576 * 2);
    bf16_t* w2_t   = (bf16_t*)takeB(8ull * 1048576 * 2);
    bf16_t* outw_t = (bf16_t*)takeB(16384000ull * 2);

    dim3 blk(256);
    const long WQKV = (long)Hn * Cdim * HDim;   // 262144 per layer
    const long LQKV = 1536L * Cdim;             // 786432 per layer (fused, transposed)

    // ================= weight prep: transpose + convert to bf16 [N,K] =================
    // fused qkv weights per set: rows [q(512) | k(512) | v(512)] x K=512
    const float* wsrc[3][3] = {{e_wq, e_wk, e_wv}, {dsa_wq, dsa_wk, dsa_wv}, {dca_wq, dca_wk, dca_wv}};
    for (int s = 0; s < 3; s++)
        for (int part = 0; part < 3; part++)
            tcvt_k<<<dim3(1, 8, 32), blk, 0, stream>>>(
                wsrc[s][part], wqkv_t + (long)s * Ld * LQKV + (long)part * 512 * Cdim,
                Cdim, HDim, WQKV, (long)Cdim * HDim, LQKV, (long)64 * Cdim, Hn);
    const float* wosrc[3] = {e_wo, dsa_wo, dca_wo};
    for (int s = 0; s < 3; s++)
        tcvt_k<<<dim3(8, 8, 4), blk, 0, stream>>>(
            wosrc[s], wo_t + (long)s * Ld * Cdim * Cdim,
            Cdim, Cdim, (long)Cdim * Cdim, 0, (long)Cdim * Cdim, 0, 1);
    tcvt_k<<<dim3(32, 8, 4), blk, 0, stream>>>(e_w1, w1_t,             Cdim, FF, (long)Cdim * FF, 0, (long)Cdim * FF, 0, 1);
    tcvt_k<<<dim3(32, 8, 4), blk, 0, stream>>>(d_w1, w1_t + 4ull * Cdim * FF, Cdim, FF, (long)Cdim * FF, 0, (long)Cdim * FF, 0, 1);
    tcvt_k<<<dim3(8, 32, 4), blk, 0, stream>>>(e_w2, w2_t,             FF, Cdim, (long)FF * Cdim, 0, (long)FF * Cdim, 0, 1);
    tcvt_k<<<dim3(8, 32, 4), blk, 0, stream>>>(d_w2, w2_t + 4ull * FF * Cdim, FF, Cdim, (long)FF * Cdim, 0, (long)FF * Cdim, 0, 1);
    tcvt_k<<<dim3(500, 8, 1), blk, 0, stream>>>(out_w, outw_t, Cdim, Vn, 0, 0, 0, 0, 1);

    // ================= encoder =================
    embed_k<<<NTOK * Cdim / 256, blk, 0, stream>>>(enc_inp, tok_emb, pos_emb, x_enc);
    for (int l = 0; l < Ld; l++) {
        ln_k<<<NTOK, blk, 0, stream>>>(x_enc, e_ln1_g + l * Cdim, e_ln1_b + l * Cdim, h);
        run_attn(stream, h, h,
                 wqkv_t + (long)l * LQKV, e_bo + l * Cdim, wo_t + (long)l * Cdim * Cdim,
                 x_enc, enc_mask, /*causal=*/false, qkv, vt, sc, ao);
        ln_k<<<NTOK, blk, 0, stream>>>(x_enc, e_ln2_g + l * Cdim, e_ln2_b + l * Cdim, h);
        mgemm_k<128,128,true,true,false,true><<<dim3(16, 16, 1), blk, 0, stream>>>(
            h, w1_t + (long)l * Cdim * FF, e_b1 + l * FF, nullptr, mid,
            Cdim, Cdim, Cdim, FF, 0,0,0,0,0,0, 1);
        mgemm_k<128,128,true,false,true,false><<<dim3(4, 16, 1), blk, 0, stream>>>(
            mid, w2_t + (long)l * FF * Cdim, e_b2 + l * Cdim, x_enc, x_enc,
            FF, FF, FF, Cdim, 0,0,0,0,0,0, 1);
    }
    // x_enc now holds enc_out

    // ================= decoder =================
    embed_k<<<NTOK * Cdim / 256, blk, 0, stream>>>(dec_inp, tok_emb, pos_emb, x_dec);
    for (int l = 0; l < Ld; l++) {
        // causal self-attention
        ln_k<<<NTOK, blk, 0, stream>>>(x_dec, d_ln1_g + l * Cdim, d_ln1_b + l * Cdim, h);
        run_attn(stream, h, h,
                 wqkv_t + (long)(Ld + l) * LQKV, dsa_bo + l * Cdim,
                 wo_t + (long)(Ld + l) * Cdim * Cdim,
                 x_dec, nullptr, /*causal=*/true, qkv, vt, sc, ao);
        // cross-attention (same LN applied to x and enc_out)
        ln_k<<<NTOK, blk, 0, stream>>>(x_dec, d_ln2_g + l * Cdim, d_ln2_b + l * Cdim, h);
        ln_k<<<NTOK, blk, 0, stream>>>(x_enc, d_ln2_g + l * Cdim, d_ln2_b + l * Cdim, hk);
        run_attn(stream, h, hk,
                 wqkv_t + (long)(2 * Ld + l) * LQKV, dca_bo + l * Cdim,
                 wo_t + (long)(2 * Ld + l) * Cdim * Cdim,
                 x_dec, enc_mask, /*causal=*/false, qkv, vt, sc, ao);
        // FFN
        ln_k<<<NTOK, blk, 0, stream>>>(x_dec, d_ln3_g + l * Cdim, d_ln3_b + l * Cdim, h);
        mgemm_k<128,128,true,true,false,true><<<dim3(16, 16, 1), blk, 0, stream>>>(
            h, w1_t + (long)(Ld + l) * Cdim * FF, d_b1 + l * FF, nullptr, mid,
            Cdim, Cdim, Cdim, FF, 0,0,0,0,0,0, 1);
        mgemm_k<128,128,true,false,true,false><<<dim3(4, 16, 1), blk, 0, stream>>>(
            mid, w2_t + (long)(Ld + l) * FF * Cdim, d_b2 + l * Cdim, x_dec, x_dec,
            FF, FF, FF, Cdim, 0,0,0,0,0,0, 1);
    }

    // ================= final logits (f32 out) =================
    cvt_k<<<NTOK * Cdim / 256, blk, 0, stream>>>(x_dec, xdb);
    mgemm_k<128,128,true,false,false,false><<<dim3(250, 16, 1), blk, 0, stream>>>(
        xdb, outw_t, out_b, nullptr, out,
        Cdim, Cdim, Cdim, Vn, 0,0,0,0,0,0, 1);
}

// Round 3
// 1321.385 us; speedup vs baseline: 6.7021x; 1.5256x over previous
//
#include <hip/hip_runtime.h>
#include <hip/hip_bf16.h>
#include <math.h>

#define Cdim 512
#define Hn   8
#define HDim 64
#define Ld   4
#define Tn   1024
#define Bn   2
#define NTOK 2048   // B*T
#define FF   2048   // 4*C
#define Vn   32000

typedef __bf16 bf16_t;
typedef __bf16 bf16x8 __attribute__((ext_vector_type(8)));
typedef __bf16 bf16x4 __attribute__((ext_vector_type(4)));
typedef float  f32x4  __attribute__((ext_vector_type(4)));

// ---------------- embedding: out[b,t,:] = tok[inp[b,t],:] + pos[t,:] (f32) ----------------
__global__ __launch_bounds__(256) void embed_k(const int* __restrict__ inp,
    const float* __restrict__ tok, const float* __restrict__ pos,
    float* __restrict__ out)
{
    int idx = blockIdx.x * 256 + threadIdx.x;   // over B*T*C
    int c  = idx & (Cdim - 1);
    int bt = idx >> 9;
    int t  = bt & (Tn - 1);
    out[idx] = tok[(long)inp[bt] * Cdim + c] + pos[t * Cdim + c];
}

// ---------------- layernorm (C=512): f32 in, bf16 out. one block per row ----------------
__global__ __launch_bounds__(256) void ln_k(const float* __restrict__ x,
    const float* __restrict__ g, const float* __restrict__ bb,
    bf16_t* __restrict__ y)
{
    __shared__ float red[4];
    int row = blockIdx.x, tid = threadIdx.x;
    const float* xr = x + (long)row * Cdim;
    float v0 = xr[tid], v1 = xr[tid + 256];
    float s = v0 + v1;
    #pragma unroll
    for (int o = 32; o > 0; o >>= 1) s += __shfl_down(s, o, 64);
    int wid = tid >> 6, lane = tid & 63;
    if (lane == 0) red[wid] = s;
    __syncthreads();
    float mean = (red[0] + red[1] + red[2] + red[3]) * (1.f / Cdim);
    __syncthreads();
    float d0 = v0 - mean, d1 = v1 - mean;
    float qv = d0 * d0 + d1 * d1;
    #pragma unroll
    for (int o = 32; o > 0; o >>= 1) qv += __shfl_down(qv, o, 64);
    if (lane == 0) red[wid] = qv;
    __syncthreads();
    float var = (red[0] + red[1] + red[2] + red[3]) * (1.f / Cdim);
    float inv = rsqrtf(var + 1e-5f);
    y[(long)row * Cdim + tid]       = (bf16_t)(d0 * inv * g[tid]       + bb[tid]);
    y[(long)row * Cdim + tid + 256] = (bf16_t)(d1 * inv * g[tid + 256] + bb[tid + 256]);
}

// ---------------- f32 -> bf16 elementwise convert ----------------
__global__ __launch_bounds__(256) void cvt_k(const float* __restrict__ x, bf16_t* __restrict__ y)
{
    int i = blockIdx.x * 256 + threadIdx.x;
    y[i] = (bf16_t)x[i];
}

// ------- tiled transpose+convert: f32 [R,Cc] -> bf16 [Cc,R]; two-level batch (zb,zh) -------
__global__ __launch_bounds__(256) void tcvt_k(const float* __restrict__ in,
    bf16_t* __restrict__ outp, int R, int Cc,
    long inOffB, long inOffH, long outOffB, long outOffH, int HB)
{
    int bz = blockIdx.z; int zb = bz / HB, zh = bz - zb * HB;
    in   += zb * inOffB  + zh * inOffH;
    outp += zb * outOffB + zh * outOffH;
    __shared__ float t[64][65];
    int r0 = blockIdx.y * 64, c0 = blockIdx.x * 64;
    int tx = threadIdx.x & 63, ty = threadIdx.x >> 6;
    #pragma unroll
    for (int i = 0; i < 16; i++)
        t[ty + i * 4][tx] = in[(long)(r0 + ty + i * 4) * Cc + c0 + tx];
    __syncthreads();
    #pragma unroll
    for (int i = 0; i < 16; i++) {
        int cc = ty + i * 4;
        outp[(long)(c0 + cc) * R + r0 + tx] = (bf16_t)t[tx][cc];
    }
}

// ================= bf16 MFMA GEMM: C = op(A @ Bt^T) =================
// A [M,K] bf16 row-major (lda), Bt [N,K] bf16 row-major (ldb).
// BM x BN tile, BK=32, 256 threads = 4 waves (2x2), 16x16x32 MFMA.
// global_load_lds width-16 staging, linear LDS. Batched via blockIdx.z -> (zb,zh).
// VOUT: output columns >= vSplit are scattered transposed into vt
//       (vt[(b*512 + (gc-vSplit))*Tn + t], b=(row>>10), t=row&1023).
template<int BM, int BN, bool BIAS, bool RELU, bool RES, bool OBF, bool VOUT>
__global__ __launch_bounds__(256) void mgemm_k(
    const bf16_t* __restrict__ A, const bf16_t* __restrict__ Bt,
    const float* __restrict__ bias, const float* __restrict__ res,
    void* __restrict__ Cout, bf16_t* __restrict__ vtout, int vSplit,
    int K, int lda, int ldb, int ldc,
    long aOffB, long aOffH, long bOffB, long bOffH, long cOffB, long cOffH, int HB)
{
    int bz = blockIdx.z;
    int zb = bz / HB, zh = bz - zb * HB;
    A  += zb * aOffB + zh * aOffH;
    Bt += zb * bOffB + zh * bOffH;
    long coff = zb * cOffB + zh * cOffH;

    constexpr int MR = BM / 32;     // 16x16 m-frags per wave
    constexpr int NR = BN / 32;
    __shared__ bf16_t As[BM * 32];
    __shared__ bf16_t Bs[BN * 32];

    int tid = threadIdx.x;
    int wv = tid >> 6, lane = tid & 63;
    int bm = blockIdx.y * BM, bn = blockIdx.x * BN;
    int wr = wv >> 1, wc = wv & 1;

    f32x4 acc[MR][NR];
    #pragma unroll
    for (int i = 0; i < MR; i++)
        #pragma unroll
        for (int j = 0; j < NR; j++)
            acc[i][j] = (f32x4){0.f, 0.f, 0.f, 0.f};

    const int srow  = lane >> 2;        // 0..15 within a 16-row staging slab
    const int scol8 = (lane & 3) * 8;   // bf16 element offset within row
    const int r16 = lane & 15, kg8 = (lane >> 4) * 8;

    for (int k0 = 0; k0 < K; k0 += 32) {
        #pragma unroll
        for (int j = 0; j < BM / 64; j++) {
            int rbase = wv * (BM / 4) + j * 16;
            const bf16_t* g = A + (long)(bm + rbase + srow) * lda + (k0 + scol8);
            __builtin_amdgcn_global_load_lds(
                (const __attribute__((address_space(1))) void*)g,
                (__attribute__((address_space(3))) void*)&As[rbase * 32],
                16, 0, 0);
        }
        #pragma unroll
        for (int j = 0; j < BN / 64; j++) {
            int rbase = wv * (BN / 4) + j * 16;
            const bf16_t* g = Bt + (long)(bn + rbase + srow) * ldb + (k0 + scol8);
            __builtin_amdgcn_global_load_lds(
                (const __attribute__((address_space(1))) void*)g,
                (__attribute__((address_space(3))) void*)&Bs[rbase * 32],
                16, 0, 0);
        }
        __syncthreads();

        bf16x8 af[MR], bfv[NR];
        #pragma unroll
        for (int i = 0; i < MR; i++)
            af[i] = *(const bf16x8*)&As[(wr * (BM / 2) + i * 16 + r16) * 32 + kg8];
        #pragma unroll
        for (int j = 0; j < NR; j++)
            bfv[j] = *(const bf16x8*)&Bs[(wc * (BN / 2) + j * 16 + r16) * 32 + kg8];
        #pragma unroll
        for (int i = 0; i < MR; i++)
            #pragma unroll
            for (int j = 0; j < NR; j++)
                acc[i][j] = __builtin_amdgcn_mfma_f32_16x16x32_bf16(af[i], bfv[j], acc[i][j], 0, 0, 0);
        __syncthreads();
    }

    // ---- epilogue: C/D layout col=lane&15, row=(lane>>4)*4+q ----
    int crow0 = (lane >> 4) * 4;
    int ccol  = lane & 15;
    #pragma unroll
    for (int i = 0; i < MR; i++) {
        #pragma unroll
        for (int j = 0; j < NR; j++) {
            int gr = bm + wr * (BM / 2) + i * 16 + crow0;
            int gc = bn + wc * (BN / 2) + j * 16 + ccol;
            float bv = BIAS ? bias[gc] : 0.f;
            #pragma unroll
            for (int q = 0; q < 4; q++) {
                float v = acc[i][j][q];
                if (BIAS) v += bv;
                if (RELU) v = fmaxf(v, 0.f);
                if (VOUT && gc >= vSplit) {
                    int row = gr + q;
                    int b = row >> 10, t = row & (Tn - 1);
                    vtout[((long)b * 512 + (gc - vSplit)) * Tn + t] = (bf16_t)v;
                } else {
                    long oidx = coff + (long)(gr + q) * ldc + gc;
                    if (RES)  v += res[oidx];
                    if (OBF) ((bf16_t*)Cout)[oidx] = (bf16_t)v;
                    else     ((float*) Cout)[oidx] = v;
                }
            }
        }
    }
}

// ================= fused flash attention =================
// grid: (T/64 q-tiles, B*H). 256 threads = 4 waves; wave w owns q-rows w*16..w*16+15.
// Q in regs; K,V^T tiles (64x64) staged reg->LDS (+8 pad); online softmax in regs;
// P bounced through per-wave padded LDS to reach MFMA A-frag layout.
template<bool CAUSAL, bool HASMASK>
__global__ __launch_bounds__(256) void flash_k(
    const bf16_t* __restrict__ qkv, const bf16_t* __restrict__ vt,
    const int* __restrict__ mask, bf16_t* __restrict__ ao)
{
    __shared__ bf16_t Kl[64][72];
    __shared__ bf16_t Vl[64][72];
    __shared__ bf16_t Pl[4][16][72];

    int qt = blockIdx.x, bh = blockIdx.y;
    int b = bh >> 3, h = bh & 7;
    int tid = threadIdx.x, wv = tid >> 6, lane = tid & 63;
    int r16 = lane & 15, g4 = lane >> 4;

    // Q A-frags: row = lane&15, k = g4*8 (+32 per k-step)
    int qrow_blk = qt * 64 + wv * 16;
    const bf16_t* qb = qkv + ((long)(b * Tn + qrow_blk + r16)) * 1536 + h * 64;
    bf16x8 aq0 = *(const bf16x8*)&qb[g4 * 8];
    bf16x8 aq1 = *(const bf16x8*)&qb[32 + g4 * 8];

    f32x4 acc[4];
    #pragma unroll
    for (int j = 0; j < 4; j++) acc[j] = (f32x4){0.f, 0.f, 0.f, 0.f};
    float m_[4], l_[4];
    #pragma unroll
    for (int q = 0; q < 4; q++) { m_[q] = -1e30f; l_[q] = 0.f; }

    int nt = CAUSAL ? (qt + 1) : (Tn / 64);
    int srow = tid >> 3;            // 0..31
    int scol = (tid & 7) * 8;

    for (int it = 0; it < nt; it++) {
        int s0 = it * 64;
        // global loads (regs)
        bf16x8 kr0 = *(const bf16x8*)&qkv[((long)(b * Tn + s0 + srow)) * 1536 + 512 + h * 64 + scol];
        bf16x8 kr1 = *(const bf16x8*)&qkv[((long)(b * Tn + s0 + srow + 32)) * 1536 + 512 + h * 64 + scol];
        bf16x8 vr0 = *(const bf16x8*)&vt[((long)(bh * 64 + srow)) * Tn + s0 + scol];
        bf16x8 vr1 = *(const bf16x8*)&vt[((long)(bh * 64 + srow + 32)) * Tn + s0 + scol];
        int mv = 0;
        if (HASMASK) mv = mask[b * Tn + s0 + lane];
        __syncthreads();                     // prior tile fully consumed
        *(bf16x8*)&Kl[srow][scol]      = kr0;
        *(bf16x8*)&Kl[srow + 32][scol] = kr1;
        *(bf16x8*)&Vl[srow][scol]      = vr0;
        *(bf16x8*)&Vl[srow + 32][scol] = vr1;
        __syncthreads();                     // tiles visible

        // ---- QK^T ----
        f32x4 sc[4];
        #pragma unroll
        for (int j = 0; j < 4; j++) {
            sc[j] = (f32x4){0.f, 0.f, 0.f, 0.f};
            bf16x8 bk0 = *(const bf16x8*)&Kl[j * 16 + r16][g4 * 8];
            bf16x8 bk1 = *(const bf16x8*)&Kl[j * 16 + r16][32 + g4 * 8];
            sc[j] = __builtin_amdgcn_mfma_f32_16x16x32_bf16(aq0, bk0, sc[j], 0, 0, 0);
            sc[j] = __builtin_amdgcn_mfma_f32_16x16x32_bf16(aq1, bk1, sc[j], 0, 0, 0);
        }

        // ---- scale + mask ----
        bool diag = CAUSAL && (it == qt);
        #pragma unroll
        for (int j = 0; j < 4; j++) {
            int scg = j * 16 + r16;          // col within tile (per lane)
            int mm = 1;
            if (HASMASK) mm = __shfl(mv, scg, 64);
            #pragma unroll
            for (int q = 0; q < 4; q++) {
                float v = sc[j][q] * 0.125f;
                if (diag) { int qr = wv * 16 + g4 * 4 + q; if (scg > qr) v = -1e30f; }
                if (HASMASK && mm == 0) v = -1e30f;
                sc[j][q] = v;
            }
        }

        // ---- online softmax (row = (g4*4+q), reduce across lane&15) ----
        #pragma unroll
        for (int q = 0; q < 4; q++) {
            float v = fmaxf(fmaxf(sc[0][q], sc[1][q]), fmaxf(sc[2][q], sc[3][q]));
            v = fmaxf(v, __shfl_xor(v, 1, 64));
            v = fmaxf(v, __shfl_xor(v, 2, 64));
            v = fmaxf(v, __shfl_xor(v, 4, 64));
            v = fmaxf(v, __shfl_xor(v, 8, 64));
            float mnew = fmaxf(m_[q], v);
            float rescale = __expf(m_[q] - mnew);
            float rs = 0.f;
            #pragma unroll
            for (int j = 0; j < 4; j++) {
                float p = __expf(sc[j][q] - mnew);
                sc[j][q] = p;
                rs += p;
            }
            rs += __shfl_xor(rs, 1, 64);
            rs += __shfl_xor(rs, 2, 64);
            rs += __shfl_xor(rs, 4, 64);
            rs += __shfl_xor(rs, 8, 64);
            l_[q] = l_[q] * rescale + rs;
            m_[q] = mnew;
            #pragma unroll
            for (int j = 0; j < 4; j++) acc[j][q] *= rescale;
        }

        // ---- P -> per-wave LDS (C/D layout -> A-frag layout) ----
        #pragma unroll
        for (int j = 0; j < 4; j++)
            #pragma unroll
            for (int q = 0; q < 4; q++)
                Pl[wv][g4 * 4 + q][j * 16 + r16] = (bf16_t)sc[j][q];
        asm volatile("s_waitcnt lgkmcnt(0)" ::: "memory");

        // ---- PV ----
        #pragma unroll
        for (int c = 0; c < 2; c++) {
            bf16x8 pa = *(const bf16x8*)&Pl[wv][r16][c * 32 + g4 * 8];
            #pragma unroll
            for (int j = 0; j < 4; j++) {
                bf16x8 bv = *(const bf16x8*)&Vl[j * 16 + r16][c * 32 + g4 * 8];
                acc[j] = __builtin_amdgcn_mfma_f32_16x16x32_bf16(pa, bv, acc[j], 0, 0, 0);
            }
        }
    }

    // ---- epilogue: O /= l, write [t][h*64+d] bf16 ----
    bf16_t* aob = ao + ((long)(b * Tn + qrow_blk + g4 * 4)) * Cdim + h * 64;
    #pragma unroll
    for (int q = 0; q < 4; q++) {
        float inv = 1.f / l_[q];
        #pragma unroll
        for (int j = 0; j < 4; j++)
            aob[(long)q * Cdim + j * 16 + r16] = (bf16_t)(acc[j][q] * inv);
    }
}

// ================================ host orchestration ================================
static void run_attn(hipStream_t stream, const bf16_t* hq, const bf16_t* hkv,
    const bf16_t* wqkv, const float* bo, const bf16_t* wo_t,
    float* xres, const int* mask, bool causal, bool selfattn,
    bf16_t* qkv, bf16_t* vt, bf16_t* ao)
{
    dim3 blk(256);
    if (selfattn) {
        // fused qkv projection: N=1536, v-part scattered to vt
        mgemm_k<64,64,false,false,false,true,true><<<dim3(24, 32, 1), blk, 0, stream>>>(
            hq, wqkv, nullptr, nullptr, qkv, vt, 1024,
            Cdim, Cdim, Cdim, 1536, 0,0,0,0,0,0, 1);
    } else {
        // q proj (N=512)
        mgemm_k<64,64,false,false,false,true,false><<<dim3(8, 32, 1), blk, 0, stream>>>(
            hq, wqkv, nullptr, nullptr, qkv, nullptr, 1 << 30,
            Cdim, Cdim, Cdim, 1536, 0,0,0,0,0,0, 1);
        // kv proj (N=1024, writes qkv cols 512.. and vt)
        mgemm_k<64,64,false,false,false,true,true><<<dim3(16, 32, 1), blk, 0, stream>>>(
            hkv, wqkv + 512 * Cdim, nullptr, nullptr, qkv + 512, vt, 512,
            Cdim, Cdim, Cdim, 1536, 0,0,0,0,0,0, 1);
    }
    if (causal)
        flash_k<true,false><<<dim3(Tn / 64, Bn * Hn), blk, 0, stream>>>(qkv, vt, nullptr, ao);
    else
        flash_k<false,true><<<dim3(Tn / 64, Bn * Hn), blk, 0, stream>>>(qkv, vt, mask, ao);
    // out projection + bias + residual (f32, in place on xres)
    mgemm_k<64,64,true,false,true,false,false><<<dim3(8, 32, 1), blk, 0, stream>>>(
        ao, wo_t, bo, xres, xres, nullptr, 1 << 30,
        Cdim, Cdim, Cdim, Cdim, 0,0,0,0,0,0, 1);
}

extern "C" void kernel_launch(void* const* d_in, const int* in_sizes, int n_in,
                              void* d_out, int out_size, void* d_ws, size_t ws_size,
                              hipStream_t stream)
{
    (void)in_sizes; (void)n_in; (void)out_size; (void)ws_size;
    const int*   enc_inp  = (const int*)d_in[0];
    const int*   dec_inp  = (const int*)d_in[1];
    const int*   enc_mask = (const int*)d_in[2];
    const float* tok_emb  = (const float*)d_in[3];
    const float* pos_emb  = (const float*)d_in[4];
    const float* e_wq  = (const float*)d_in[5];
    const float* e_wk  = (const float*)d_in[6];
    const float* e_wv  = (const float*)d_in[7];
    const float* e_wo  = (const float*)d_in[8];
    const float* e_bo  = (const float*)d_in[9];
    const float* dsa_wq = (const float*)d_in[10];
    const float* dsa_wk = (const float*)d_in[11];
    const float* dsa_wv = (const float*)d_in[12];
    const float* dsa_wo = (const float*)d_in[13];
    const float* dsa_bo = (const float*)d_in[14];
    const float* dca_wq = (const float*)d_in[15];
    const float* dca_wk = (const float*)d_in[16];
    const float* dca_wv = (const float*)d_in[17];
    const float* dca_wo = (const float*)d_in[18];
    const float* dca_bo = (const float*)d_in[19];
    const float* e_ln1_g = (const float*)d_in[20];
    const float* e_ln1_b = (const float*)d_in[21];
    const float* e_ln2_g = (const float*)d_in[22];
    const float* e_ln2_b = (const float*)d_in[23];
    const float* d_ln1_g = (const float*)d_in[24];
    const float* d_ln1_b = (const float*)d_in[25];
    const float* d_ln2_g = (const float*)d_in[26];
    const float* d_ln2_b = (const float*)d_in[27];
    const float* d_ln3_g = (const float*)d_in[28];
    const float* d_ln3_b = (const float*)d_in[29];
    const float* e_w1 = (const float*)d_in[30];
    const float* e_b1 = (const float*)d_in[31];
    const float* e_w2 = (const float*)d_in[32];
    const float* e_b2 = (const float*)d_in[33];
    const float* d_w1 = (const float*)d_in[34];
    const float* d_b1 = (const float*)d_in[35];
    const float* d_w2 = (const float*)d_in[36];
    const float* d_b2 = (const float*)d_in[37];
    const float* out_w = (const float*)d_in[38];
    const float* out_b = (const float*)d_in[39];
    float* out = (float*)d_out;

    // -------- workspace carve (bytes) --------
    char* p = (char*)d_ws;
    auto takeB = [&](size_t bytes) { char* r = p; p += (bytes + 255) & ~(size_t)255; return r; };
    float*  x_enc = (float*)takeB(1048576ull * 4);
    float*  x_dec = (float*)takeB(1048576ull * 4);
    bf16_t* h     = (bf16_t*)takeB(1048576ull * 2);
    bf16_t* hk    = (bf16_t*)takeB(1048576ull * 2);
    bf16_t* qkv   = (bf16_t*)takeB(3145728ull * 2);
    bf16_t* vt    = (bf16_t*)takeB(1048576ull * 2);
    bf16_t* ao    = (bf16_t*)takeB(1048576ull * 2);
    bf16_t* xdb   = (bf16_t*)takeB(1048576ull * 2);
    bf16_t* mid   = (bf16_t*)takeB(4194304ull * 2);
    bf16_t* wqkv_t = (bf16_t*)takeB(12ull * 786432 * 2);
    bf16_t* wo_t   = (bf16_t*)takeB(12ull * 262144 * 2);
    bf16_t* w1_t   = (bf16_t*)takeB(8ull * 1048576 * 2);
    bf16_t* w2_t   = (bf16_t*)takeB(8ull * 1048576 * 2);
    bf16_t* outw_t = (bf16_t*)takeB(16384000ull * 2);

    dim3 blk(256);
    const long WQKV = (long)Hn * Cdim * HDim;   // 262144 per layer
    const long LQKV = 1536L * Cdim;             // 786432 per layer (fused, transposed)

    // ================= weight prep: transpose + convert to bf16 [N,K] =================
    const float* wsrc[3][3] = {{e_wq, e_wk, e_wv}, {dsa_wq, dsa_wk, dsa_wv}, {dca_wq, dca_wk, dca_wv}};
    for (int s = 0; s < 3; s++)
        for (int part = 0; part < 3; part++)
            tcvt_k<<<dim3(1, 8, 32), blk, 0, stream>>>(
                wsrc[s][part], wqkv_t + (long)s * Ld * LQKV + (long)part * 512 * Cdim,
                Cdim, HDim, WQKV, (long)Cdim * HDim, LQKV, (long)64 * Cdim, Hn);
    const float* wosrc[3] = {e_wo, dsa_wo, dca_wo};
    for (int s = 0; s < 3; s++)
        tcvt_k<<<dim3(8, 8, 4), blk, 0, stream>>>(
            wosrc[s], wo_t + (long)s * Ld * Cdim * Cdim,
            Cdim, Cdim, (long)Cdim * Cdim, 0, (long)Cdim * Cdim, 0, 1);
    tcvt_k<<<dim3(32, 8, 4), blk, 0, stream>>>(e_w1, w1_t,             Cdim, FF, (long)Cdim * FF, 0, (long)Cdim * FF, 0, 1);
    tcvt_k<<<dim3(32, 8, 4), blk, 0, stream>>>(d_w1, w1_t + 4ull * Cdim * FF, Cdim, FF, (long)Cdim * FF, 0, (long)Cdim * FF, 0, 1);
    tcvt_k<<<dim3(8, 32, 4), blk, 0, stream>>>(e_w2, w2_t,             FF, Cdim, (long)FF * Cdim, 0, (long)FF * Cdim, 0, 1);
    tcvt_k<<<dim3(8, 32, 4), blk, 0, stream>>>(d_w2, w2_t + 4ull * FF * Cdim, FF, Cdim, (long)FF * Cdim, 0, (long)FF * Cdim, 0, 1);
    tcvt_k<<<dim3(500, 8, 1), blk, 0, stream>>>(out_w, outw_t, Cdim, Vn, 0, 0, 0, 0, 1);

    // ================= encoder =================
    embed_k<<<NTOK * Cdim / 256, blk, 0, stream>>>(enc_inp, tok_emb, pos_emb, x_enc);
    for (int l = 0; l < Ld; l++) {
        ln_k<<<NTOK, blk, 0, stream>>>(x_enc, e_ln1_g + l * Cdim, e_ln1_b + l * Cdim, h);
        run_attn(stream, h, h,
                 wqkv_t + (long)l * LQKV, e_bo + l * Cdim, wo_t + (long)l * Cdim * Cdim,
                 x_enc, enc_mask, /*causal=*/false, /*self=*/true, qkv, vt, ao);
        ln_k<<<NTOK, blk, 0, stream>>>(x_enc, e_ln2_g + l * Cdim, e_ln2_b + l * Cdim, h);
        mgemm_k<128,128,true,true,false,true,false><<<dim3(16, 16, 1), blk, 0, stream>>>(
            h, w1_t + (long)l * Cdim * FF, e_b1 + l * FF, nullptr, mid, nullptr, 1 << 30,
            Cdim, Cdim, Cdim, FF, 0,0,0,0,0,0, 1);
        mgemm_k<64,64,true,false,true,false,false><<<dim3(8, 32, 1), blk, 0, stream>>>(
            mid, w2_t + (long)l * FF * Cdim, e_b2 + l * Cdim, x_enc, x_enc, nullptr, 1 << 30,
            FF, FF, FF, Cdim, 0,0,0,0,0,0, 1);
    }
    // x_enc now holds enc_out

    // ================= decoder =================
    embed_k<<<NTOK * Cdim / 256, blk, 0, stream>>>(dec_inp, tok_emb, pos_emb, x_dec);
    for (int l = 0; l < Ld; l++) {
        // causal self-attention
        ln_k<<<NTOK, blk, 0, stream>>>(x_dec, d_ln1_g + l * Cdim, d_ln1_b + l * Cdim, h);
        run_attn(stream, h, h,
                 wqkv_t + (long)(Ld + l) * LQKV, dsa_bo + l * Cdim,
                 wo_t + (long)(Ld + l) * Cdim * Cdim,
                 x_dec, nullptr, /*causal=*/true, /*self=*/true, qkv, vt, ao);
        // cross-attention (same LN applied to x and enc_out)
        ln_k<<<NTOK, blk, 0, stream>>>(x_dec, d_ln2_g + l * Cdim, d_ln2_b + l * Cdim, h);
        ln_k<<<NTOK, blk, 0, stream>>>(x_enc, d_ln2_g + l * Cdim, d_ln2_b + l * Cdim, hk);
        run_attn(stream, h, hk,
                 wqkv_t + (long)(2 * Ld + l) * LQKV, dca_bo + l * Cdim,
                 wo_t + (long)(2 * Ld + l) * Cdim * Cdim,
                 x_dec, enc_mask, /*causal=*/false, /*self=*/false, qkv, vt, ao);
        // FFN
        ln_k<<<NTOK, blk, 0, stream>>>(x_dec, d_ln3_g + l * Cdim, d_ln3_b + l * Cdim, h);
        mgemm_k<128,128,true,true,false,true,false><<<dim3(16, 16, 1), blk, 0, stream>>>(
            h, w1_t + (long)(Ld + l) * Cdim * FF, d_b1 + l * FF, nullptr, mid, nullptr, 1 << 30,
            Cdim, Cdim, Cdim, FF, 0,0,0,0,0,0, 1);
        mgemm_k<64,64,true,false,true,false,false><<<dim3(8, 32, 1), blk, 0, stream>>>(
            mid, w2_t + (long)(Ld + l) * FF * Cdim, d_b2 + l * Cdim, x_dec, x_dec, nullptr, 1 << 30,
            FF, FF, FF, Cdim, 0,0,0,0,0,0, 1);
    }

    // ================= final logits (f32 out) =================
    cvt_k<<<NTOK * Cdim / 256, blk, 0, stream>>>(x_dec, xdb);
    mgemm_k<128,128,true,false,false,false,false><<<dim3(250, 16, 1), blk, 0, stream>>>(
        xdb, outw_t, out_b, nullptr, out, nullptr, 1 << 30,
        Cdim, Cdim, Cdim, Vn, 0,0,0,0,0,0, 1);
}